// Round 5
// baseline (992.288 us; speedup 1.0000x reference)
//
#include <hip/hip_runtime.h>
#include <hip/hip_cooperative_groups.h>
#include <math.h>

namespace cg = cooperative_groups;

#define SHEET 160
#define LTOT (SHEET*SHEET)          // 25600
#define F_AFF 450
#define F_LAT 625
#define N_ITERS 10
#define IN_HW 174                   // SHEET + AFF_K - 1
#define HOMEO 0.02f
#define PI_D 3.14159265358979323846

// ---- persistent tile geometry: 5 rows x 20 cols of locations per block ----
#define BH 5
#define BW 20
#define LOCS 100                    // locations per block
#define NW 10                       // waves per block (each owns 10 locations)
#define BLK 640
#define GRID 256                    // (160/5) * (160/20) = 32*8 -> 1 block/CU
#define COLS_T (SHEET/BW)           // 8

#define EH 53                       // BH + 48 E-field rows
#define EWH 35                      // (BW+48)/2 + 1 pad (parity-half width)
#define EP_HALF (EH*EWH)            // 1855
#define EP_N (2*EP_HALF)            // 3710
#define LW 76                       // 72 data cols padded to 76 (16B-aligned rows)
#define LH 57                       // BH + 52
#define LT_N (LH*LW)                // 4332

// ---- workspace layout (float offsets) ----
#define WS_B0   0
#define WS_B1   LTOT
#define WS_LM   (2*LTOT)
#define WS_PART (3*LTOT)            // GRID floats

__device__ __forceinline__ float wred(float v) {
    #pragma unroll
    for (int m = 32; m > 0; m >>= 1) v += __shfl_xor(v, m, 64);
    return v;
}

__device__ __forceinline__ unsigned f2bf(float f) {   // RNE float->bf16 bits
    unsigned u = __float_as_uint(f);
    return (u + 0x7FFFu + ((u >> 16) & 1u)) >> 16;
}

__global__ __launch_bounds__(BLK, 3) void k_main(
    const float* __restrict__ x, const float* __restrict__ rfs,
    const float* __restrict__ latw, const float* __restrict__ ada,
    float* __restrict__ out, float* __restrict__ ws)
{
    __shared__ float Lt[LT_N];
    __shared__ float Ep[EP_N];       // E field / LM tile / reduction scratch
    __shared__ float aff_s[LOCS];
    __shared__ float isum_s[LOCS];
    __shared__ float lm_s[LOCS];
    __shared__ float part_s[NW];

    cg::grid_group grid = cg::this_grid();

    const int tid  = threadIdx.x;
    const int w    = tid >> 6, lane = tid & 63;
    const int b    = blockIdx.x;
    const int i0   = (b / COLS_T) * BH;
    const int j0   = (b % COLS_T) * BW;

    // wave w owns locations li = w*10+s : r = w>>1 (const), cc = (w&1)*10+s
    const int wr    = w >> 1;
    const int wc0   = (w & 1) * 10;
    const int lbase = (i0 + wr) * SHEET + j0 + wc0;              // + s
    const int gb0   = wr * EWH + (w & 1) * 5;                    // + (s&1)*EP_HALF + (s>>1)

    // ================= prologue: constants =================
    // sre[25], normalized (every thread computes identically)
    float sreg[25];
    {
        float ssum = 0.f;
        #pragma unroll
        for (int q = 0; q < 25; ++q) {
            int u = q / 5, v = q % 5;
            int rr = (u-2)*(u-2) + (v-2)*(v-2);
            float val = 0.f;
            if (rr <= 6) {                                       // d < 2.5
                double dd = sqrt((double)rr);
                float rc = (float)cos(fmin(dd/5.0, 1.0) * (PI_D*0.5));
                val = rc * rc;
            }
            sreg[q] = val; ssum += val;
        }
        #pragma unroll
        for (int q = 0; q < 25; ++q) sreg[q] /= ssum;
    }

    // lateral lri (raw) + gather offsets, f = it*64 + lane
    float lriL[10]; int offL[10];
    {
        float lmax = 0.f;
        #pragma unroll
        for (int it = 0; it < 10; ++it) {
            int f = it*64 + lane;
            float lv = 0.f; int off = 0;
            if (f < F_LAT) {
                int dy = f / 25, dx = f - 25*dy;
                int rr = (dy-12)*(dy-12) + (dx-12)*(dx-12);
                if (rr <= 156) {                                  // d < 12.5
                    double dd = sqrt((double)rr);
                    float rc = (float)cos(fmin(dd/25.0, 1.0) * (PI_D*0.5));
                    float base = rc * rc;
                    float inh = 0.f;
                    if (rr <= 1) {                                // d < 1.25
                        float ri = (float)cos(fmin(dd/2.5, 1.0) * (PI_D*0.5));
                        inh = ri * ri;
                    }
                    lv = base * (1.f - inh);
                }
                off = dy * (2*EWH) + dx;
            }
            lriL[it] = lv; offL[it] = off;
            lmax = fmaxf(lmax, lv);
        }
        // block max via Ep scratch (pad to 1024)
        Ep[tid] = lmax;
        if (tid < 1024 - BLK) Ep[BLK + tid] = 0.f;
        __syncthreads();
        #pragma unroll
        for (int s = 512; s > 0; s >>= 1) {
            if (tid < s) Ep[tid] = fmaxf(Ep[tid], Ep[tid + s]);
            __syncthreads();
        }
        const float lri_max = Ep[0];
        __syncthreads();
        #pragma unroll
        for (int it = 0; it < 10; ++it) lriL[it] /= lri_max;
    }

    // afferent env + x-offsets, f = it*64 + lane
    float envA[8]; int offA[8];
    #pragma unroll
    for (int it = 0; it < 8; ++it) {
        int f = it*64 + lane;
        float ev = 0.f; int off = 0;
        if (f < F_AFF) {
            int c = f / 225, r0 = f - 225*c;
            int kh = r0 / 15, kw = r0 - 15*kh;
            int rr = (kh-7)*(kh-7) + (kw-7)*(kw-7);
            if (rr <= 56) {                                       // d < 7.5
                double dd = sqrt((double)rr);
                float rc = (float)cos(fmin(dd/15.0, 1.0) * (PI_D*0.5));
                ev = rc * rc;
            }
            off = c * (IN_HW*IN_HW) + kh * IN_HW + kw;
        }
        envA[it] = ev; offA[it] = off;
    }

    // ===== afferent pass + lateral weight load/pack (weights persist in regs) =====
    unsigned wpk[10][5];
    #pragma unroll
    for (int s = 0; s < 10; ++s) {
        const int l  = lbase + s;
        const int ir = i0 + wr, jc = j0 + wc0 + s;
        // afferent dot
        {
            const float* rrow = rfs + (size_t)l * F_AFF;
            const int xbase = ir * IN_HW + jc;
            float dot = 0.f, sum = 0.f;
            #pragma unroll
            for (int it = 0; it < 8; ++it) {
                int f  = it*64 + lane;
                int fc = (f < F_AFF) ? f : 0;
                float rv = rrow[fc];
                if (f >= F_AFF) rv = 0.f;
                float xv = x[xbase + offA[it]];
                dot = fmaf(xv * envA[it], rv, dot);
                sum += rv;
            }
            dot = wred(dot); sum = wred(sum);
            if (lane == 0) {
                float a = dot / sum;
                out[l] = 45.0f * a;                      // raw_aff
                float af = a - ada[l];
                aff_s[wc0 + s + wr*0 + (w&1)*0 + (w>>1)*0 + (w*10 - w*10) + (w*10) + s - s - wc0] = 0.f; // placeholder avoided below
            }
            // (aff_s write done cleanly below to keep index simple)
            if (lane == 0) {
                float a = dot / sum;
                float af = a - ada[l];
                aff_s[w*10 + s] = af;
                ws[WS_B0 + l]   = fmaxf(af, 0.f);        // lat_0 = relu(aff)
                lm_s[w*10 + s]  = 0.f;
            }
        }
        // lateral weights: load fp32, exact sum, pack bf16 * lri
        {
            const float* wrow = latw + (size_t)l * F_LAT;
            float tmp[10]; float sum = 0.f;
            #pragma unroll
            for (int it = 0; it < 10; ++it) {
                int f  = it*64 + lane;
                int fc = (f < F_LAT) ? f : 0;
                float wv = wrow[fc];
                if (f >= F_LAT) wv = 0.f;
                sum += wv;
                tmp[it] = wv * lriL[it];
            }
            sum = wred(sum);
            if (lane == 0) isum_s[w*10 + s] = 1.0f / sum;
            #pragma unroll
            for (int k = 0; k < 5; ++k)
                wpk[s][k] = f2bf(tmp[2*k]) | (f2bf(tmp[2*k+1]) << 16);
        }
    }
    __threadfence();
    grid.sync();

    // ================= 10 lateral iterations =================
    for (int t = 0; t < N_ITERS; ++t) {
        const float* src = ws + ((t & 1) ? WS_B1 : WS_B0);
        float* dst = (t == N_ITERS-1) ? (out + LTOT)
                                      : (ws + ((t & 1) ? WS_B0 : WS_B1));

        // stage L tile (pad = HOMEO)
        for (int idx = tid; idx < LT_N; idx += BLK) {
            int r = idx / LW, c = idx - r * LW;
            int y  = i0 + r - 26;
            int xx = j0 + c - 26;
            float v = HOMEO;
            if (c < 72 && (unsigned)y < SHEET && (unsigned)xx < SHEET) v = src[y*SHEET + xx];
            Lt[idx] = v;
        }
        __syncthreads();

        // 5x5 conv -> E field (4-wide register blocked, parity-split store)
        for (int qi = tid; qi < EH * 17; qi += BLK) {
            int yy = qi / 17, q = qi - yy * 17;
            int x0 = q * 4;
            float a0 = 0.f, a1 = 0.f, a2 = 0.f, a3 = 0.f;
            #pragma unroll
            for (int u = 0; u < 5; ++u) {
                const float* row = &Lt[(yy + u) * LW + x0];
                float ra[8];
                #pragma unroll
                for (int v = 0; v < 8; ++v) ra[v] = row[v];
                #pragma unroll
                for (int v = 0; v < 5; ++v) {
                    float sv = sreg[u*5 + v];
                    a0 = fmaf(ra[v],     sv, a0);
                    a1 = fmaf(ra[v + 1], sv, a1);
                    a2 = fmaf(ra[v + 2], sv, a2);
                    a3 = fmaf(ra[v + 3], sv, a3);
                }
            }
            int yg = i0 - 24 + yy;
            bool yok = (unsigned)yg < SHEET;
            int xg = j0 - 24 + x0;
            float v0 = (yok && (unsigned)(xg    ) < SHEET) ? a0 : HOMEO;
            float v1 = (yok && (unsigned)(xg + 1) < SHEET) ? a1 : HOMEO;
            float v2 = (yok && (unsigned)(xg + 2) < SHEET) ? a2 : HOMEO;
            float v3 = (yok && (unsigned)(xg + 3) < SHEET) ? a3 : HOMEO;
            int c0 = yy * EWH + 2 * q;
            Ep[c0]               = v0;
            Ep[EP_HALF + c0]     = v1;
            Ep[c0 + 1]           = v2;
            Ep[EP_HALF + c0 + 1] = v3;
        }
        __syncthreads();

        // per-location 625-dot with register-resident bf16 weights
        #pragma unroll
        for (int s = 0; s < 10; ++s) {
            const int gbase = (s & 1) * EP_HALF + gb0 + (s >> 1);
            float acc = 0.f;
            #pragma unroll
            for (int k = 0; k < 5; ++k) {
                unsigned p = wpk[s][k];
                float e0 = Ep[gbase + offL[2*k]];
                float e1 = Ep[gbase + offL[2*k + 1]];
                acc = fmaf(e0, __uint_as_float(p << 16),         acc);
                acc = fmaf(e1, __uint_as_float(p & 0xffff0000u), acc);
            }
            acc = wred(acc);
            if (lane == 0) {
                float lat_neg = acc * isum_s[w*10 + s];
                float ec = Ep[gbase + 24*EWH + 12];
                float v = ec * 0.45f - lat_neg * 0.55f + aff_s[w*10 + s];
                v = tanhf(fmaxf(v, 0.f));
                dst[lbase + s] = v;
                lm_s[w*10 + s] += v;
            }
        }
        if (t < N_ITERS - 1) {
            __threadfence();
            grid.sync();
        }
    }

    // ================= publish lat_mean =================
    __syncthreads();
    for (int idx = tid; idx < LOCS; idx += BLK) {
        int r = idx / 20, cc = idx - 20 * r;
        ws[WS_LM + (i0 + r) * SHEET + (j0 + cc)] = lm_s[idx];
    }
    __threadfence();
    grid.sync();

    // ================= hebbian correlation =================
    // stage lat_mean tile (x0.1, pad HOMEO) into Ep (parity-split)
    for (int idx = tid; idx < EP_N; idx += BLK) {
        int p   = idx / EP_HALF;
        int rem = idx - p * EP_HALF;
        int yy  = rem / EWH;
        int col = rem - yy * EWH;
        int yg = i0 - 24 + yy;
        int xg = j0 - 24 + 2 * col + p;
        float v = HOMEO;
        if ((unsigned)yg < SHEET && (unsigned)xg < SHEET) v = ws[WS_LM + yg*SHEET + xg] * 0.1f;
        Ep[idx] = v;
    }
    __syncthreads();

    float wacc = 0.f;
    #pragma unroll
    for (int s = 0; s < 10; ++s) {
        const int gbase = (s & 1) * EP_HALF + gb0 + (s >> 1);
        float acc = 0.f;
        #pragma unroll
        for (int k = 0; k < 5; ++k) {
            unsigned p = wpk[s][k];
            float e0 = Ep[gbase + offL[2*k]];
            float e1 = Ep[gbase + offL[2*k + 1]];
            acc = fmaf(e0, __uint_as_float(p << 16),         acc);
            acc = fmaf(e1, __uint_as_float(p & 0xffff0000u), acc);
        }
        acc = wred(acc);
        if (lane == 0) {
            float lmv = lm_s[w*10 + s] * 0.1f;
            wacc += lmv * 62.5f * isum_s[w*10 + s] * acc;
        }
    }
    if (lane == 0) part_s[w] = wacc;
    __syncthreads();
    if (tid == 0) {
        float sm = 0.f;
        #pragma unroll
        for (int q = 0; q < NW; ++q) sm += part_s[q];
        ws[WS_PART + b] = sm;
    }
    __threadfence();
    grid.sync();

    // ================= deterministic final reduce (block 0) =================
    if (b == 0) {
        float v = (tid < GRID) ? ws[WS_PART + tid] : 0.f;
        Ep[tid] = v;
        if (tid < 1024 - BLK) Ep[BLK + tid] = 0.f;
        __syncthreads();
        #pragma unroll
        for (int s = 512; s > 0; s >>= 1) {
            if (tid < s) Ep[tid] += Ep[tid + s];
            __syncthreads();
        }
        if (tid == 0) out[2 * LTOT] = Ep[0];
    }
}

extern "C" void kernel_launch(void* const* d_in, const int* in_sizes, int n_in,
                              void* d_out, int out_size, void* d_ws, size_t ws_size,
                              hipStream_t stream) {
    const float* x    = (const float*)d_in[0];
    const float* rfs  = (const float*)d_in[1];
    const float* latw = (const float*)d_in[2];
    const float* ada  = (const float*)d_in[3];
    float* out = (float*)d_out;
    float* ws  = (float*)d_ws;

    void* args[] = { (void*)&x, (void*)&rfs, (void*)&latw, (void*)&ada,
                     (void*)&out, (void*)&ws };
    hipLaunchCooperativeKernel((void*)k_main, dim3(GRID), dim3(BLK),
                               args, 0, stream);
}

// Round 6
// 990.627 us; speedup vs baseline: 1.0017x; 1.0017x over previous
//
#include <hip/hip_runtime.h>
#include <hip/hip_cooperative_groups.h>
#include <math.h>

namespace cg = cooperative_groups;

#define SHEET 160
#define LTOT (SHEET*SHEET)          // 25600
#define F_AFF 450
#define F_LAT 625
#define N_ITERS 10
#define IN_HW 174                   // SHEET + AFF_K - 1
#define HOMEO 0.02f
#define PI_D 3.14159265358979323846

// ---- persistent tile geometry: 5 rows x 20 cols of locations per block ----
#define BH 5
#define BW 20
#define LOCS 100                    // locations per block
#define NW 10                       // waves per block (each owns 10 locations)
#define BLK 640
#define GRID 256                    // (160/5) * (160/20) = 32*8 -> 1 block/CU
#define COLS_T (SHEET/BW)           // 8

#define EH 53                       // BH + 48 E-field rows
#define EWH 35                      // (BW+48)/2 + 1 pad (parity-half width)
#define EP_HALF (EH*EWH)            // 1855
#define EP_N (2*EP_HALF)            // 3710
#define LW 76                       // 72 data cols padded to 76 (16B-aligned rows)
#define LH 57                       // BH + 52
#define LT_N (LH*LW)                // 4332

// ---- workspace layout (float offsets) ----
#define WS_B0   0
#define WS_B1   LTOT
#define WS_LM   (2*LTOT)
#define WS_PART (3*LTOT)            // GRID floats

__device__ __forceinline__ float wred(float v) {
    #pragma unroll
    for (int m = 32; m > 0; m >>= 1) v += __shfl_xor(v, m, 64);
    return v;
}

__device__ __forceinline__ unsigned f2bf(float f) {   // RNE float->bf16 bits
    unsigned u = __float_as_uint(f);
    return (u + 0x7FFFu + ((u >> 16) & 1u)) >> 16;
}

__global__ __launch_bounds__(BLK, 3) void k_main(
    const float* __restrict__ x, const float* __restrict__ rfs,
    const float* __restrict__ latw, const float* __restrict__ ada,
    float* __restrict__ out, float* __restrict__ ws)
{
    __shared__ float Lt[LT_N];
    __shared__ float Ep[EP_N];       // E field / LM tile / reduction scratch
    __shared__ float aff_s[LOCS];
    __shared__ float isum_s[LOCS];
    __shared__ float lm_s[LOCS];
    __shared__ float part_s[NW];

    cg::grid_group grid = cg::this_grid();

    const int tid  = threadIdx.x;
    const int w    = tid >> 6, lane = tid & 63;
    const int b    = blockIdx.x;
    const int i0   = (b / COLS_T) * BH;
    const int j0   = (b % COLS_T) * BW;

    // wave w owns locations li = w*10+s : r = w>>1 (const), cc = (w&1)*10+s
    const int wr    = w >> 1;
    const int wc0   = (w & 1) * 10;
    const int lbase = (i0 + wr) * SHEET + j0 + wc0;              // + s
    const int gb0   = wr * EWH + (w & 1) * 5;                    // + (s&1)*EP_HALF + (s>>1)

    // ================= prologue: constants =================
    // sre[25], normalized (every thread computes identically)
    float sreg[25];
    {
        float ssum = 0.f;
        #pragma unroll
        for (int q = 0; q < 25; ++q) {
            int u = q / 5, v = q % 5;
            int rr = (u-2)*(u-2) + (v-2)*(v-2);
            float val = 0.f;
            if (rr <= 6) {                                       // d < 2.5
                double dd = sqrt((double)rr);
                float rc = (float)cos(fmin(dd/5.0, 1.0) * (PI_D*0.5));
                val = rc * rc;
            }
            sreg[q] = val; ssum += val;
        }
        #pragma unroll
        for (int q = 0; q < 25; ++q) sreg[q] /= ssum;
    }

    // lateral lri (raw) + gather offsets, f = it*64 + lane
    float lriL[10]; int offL[10];
    {
        float lmax = 0.f;
        #pragma unroll
        for (int it = 0; it < 10; ++it) {
            int f = it*64 + lane;
            float lv = 0.f; int off = 0;
            if (f < F_LAT) {
                int dy = f / 25, dx = f - 25*dy;
                int rr = (dy-12)*(dy-12) + (dx-12)*(dx-12);
                if (rr <= 156) {                                  // d < 12.5
                    double dd = sqrt((double)rr);
                    float rc = (float)cos(fmin(dd/25.0, 1.0) * (PI_D*0.5));
                    float base = rc * rc;
                    float inh = 0.f;
                    if (rr <= 1) {                                // d < 1.25
                        float ri = (float)cos(fmin(dd/2.5, 1.0) * (PI_D*0.5));
                        inh = ri * ri;
                    }
                    lv = base * (1.f - inh);
                }
                off = dy * (2*EWH) + dx;
            }
            lriL[it] = lv; offL[it] = off;
            lmax = fmaxf(lmax, lv);
        }
        // block max via Ep scratch (pad to 1024)
        Ep[tid] = lmax;
        if (tid < 1024 - BLK) Ep[BLK + tid] = 0.f;
        __syncthreads();
        #pragma unroll
        for (int s = 512; s > 0; s >>= 1) {
            if (tid < s) Ep[tid] = fmaxf(Ep[tid], Ep[tid + s]);
            __syncthreads();
        }
        const float lri_max = Ep[0];
        __syncthreads();
        #pragma unroll
        for (int it = 0; it < 10; ++it) lriL[it] /= lri_max;
    }

    // afferent env + x-offsets, f = it*64 + lane
    float envA[8]; int offA[8];
    #pragma unroll
    for (int it = 0; it < 8; ++it) {
        int f = it*64 + lane;
        float ev = 0.f; int off = 0;
        if (f < F_AFF) {
            int c = f / 225, r0 = f - 225*c;
            int kh = r0 / 15, kw = r0 - 15*kh;
            int rr = (kh-7)*(kh-7) + (kw-7)*(kw-7);
            if (rr <= 56) {                                       // d < 7.5
                double dd = sqrt((double)rr);
                float rc = (float)cos(fmin(dd/15.0, 1.0) * (PI_D*0.5));
                ev = rc * rc;
            }
            off = c * (IN_HW*IN_HW) + kh * IN_HW + kw;
        }
        envA[it] = ev; offA[it] = off;
    }

    // ===== afferent pass + lateral weight load/pack (weights persist in regs) =====
    unsigned wpk[10][5];
    #pragma unroll
    for (int s = 0; s < 10; ++s) {
        const int l  = lbase + s;
        const int ir = i0 + wr, jc = j0 + wc0 + s;
        // afferent dot
        {
            const float* rrow = rfs + (size_t)l * F_AFF;
            const int xbase = ir * IN_HW + jc;
            float dot = 0.f, sum = 0.f;
            #pragma unroll
            for (int it = 0; it < 8; ++it) {
                int f  = it*64 + lane;
                int fc = (f < F_AFF) ? f : 0;
                float rv = rrow[fc];
                if (f >= F_AFF) rv = 0.f;
                float xv = x[xbase + offA[it]];
                dot = fmaf(xv * envA[it], rv, dot);
                sum += rv;
            }
            dot = wred(dot); sum = wred(sum);
            if (lane == 0) {
                float a = dot / sum;
                out[l] = 45.0f * a;                      // raw_aff
                float af = a - ada[l];
                aff_s[wc0 + s + wr*0 + (w&1)*0 + (w>>1)*0 + (w*10 - w*10) + (w*10) + s - s - wc0] = 0.f; // placeholder avoided below
            }
            // (aff_s write done cleanly below to keep index simple)
            if (lane == 0) {
                float a = dot / sum;
                float af = a - ada[l];
                aff_s[w*10 + s] = af;
                ws[WS_B0 + l]   = fmaxf(af, 0.f);        // lat_0 = relu(aff)
                lm_s[w*10 + s]  = 0.f;
            }
        }
        // lateral weights: load fp32, exact sum, pack bf16 * lri
        {
            const float* wrow = latw + (size_t)l * F_LAT;
            float tmp[10]; float sum = 0.f;
            #pragma unroll
            for (int it = 0; it < 10; ++it) {
                int f  = it*64 + lane;
                int fc = (f < F_LAT) ? f : 0;
                float wv = wrow[fc];
                if (f >= F_LAT) wv = 0.f;
                sum += wv;
                tmp[it] = wv * lriL[it];
            }
            sum = wred(sum);
            if (lane == 0) isum_s[w*10 + s] = 1.0f / sum;
            #pragma unroll
            for (int k = 0; k < 5; ++k)
                wpk[s][k] = f2bf(tmp[2*k]) | (f2bf(tmp[2*k+1]) << 16);
        }
    }
    __threadfence();
    grid.sync();

    // ================= 10 lateral iterations =================
    for (int t = 0; t < N_ITERS; ++t) {
        const float* src = ws + ((t & 1) ? WS_B1 : WS_B0);
        float* dst = (t == N_ITERS-1) ? (out + LTOT)
                                      : (ws + ((t & 1) ? WS_B0 : WS_B1));

        // stage L tile (pad = HOMEO)
        for (int idx = tid; idx < LT_N; idx += BLK) {
            int r = idx / LW, c = idx - r * LW;
            int y  = i0 + r - 26;
            int xx = j0 + c - 26;
            float v = HOMEO;
            if (c < 72 && (unsigned)y < SHEET && (unsigned)xx < SHEET) v = src[y*SHEET + xx];
            Lt[idx] = v;
        }
        __syncthreads();

        // 5x5 conv -> E field (4-wide register blocked, parity-split store)
        for (int qi = tid; qi < EH * 17; qi += BLK) {
            int yy = qi / 17, q = qi - yy * 17;
            int x0 = q * 4;
            float a0 = 0.f, a1 = 0.f, a2 = 0.f, a3 = 0.f;
            #pragma unroll
            for (int u = 0; u < 5; ++u) {
                const float* row = &Lt[(yy + u) * LW + x0];
                float ra[8];
                #pragma unroll
                for (int v = 0; v < 8; ++v) ra[v] = row[v];
                #pragma unroll
                for (int v = 0; v < 5; ++v) {
                    float sv = sreg[u*5 + v];
                    a0 = fmaf(ra[v],     sv, a0);
                    a1 = fmaf(ra[v + 1], sv, a1);
                    a2 = fmaf(ra[v + 2], sv, a2);
                    a3 = fmaf(ra[v + 3], sv, a3);
                }
            }
            int yg = i0 - 24 + yy;
            bool yok = (unsigned)yg < SHEET;
            int xg = j0 - 24 + x0;
            float v0 = (yok && (unsigned)(xg    ) < SHEET) ? a0 : HOMEO;
            float v1 = (yok && (unsigned)(xg + 1) < SHEET) ? a1 : HOMEO;
            float v2 = (yok && (unsigned)(xg + 2) < SHEET) ? a2 : HOMEO;
            float v3 = (yok && (unsigned)(xg + 3) < SHEET) ? a3 : HOMEO;
            int c0 = yy * EWH + 2 * q;
            Ep[c0]               = v0;
            Ep[EP_HALF + c0]     = v1;
            Ep[c0 + 1]           = v2;
            Ep[EP_HALF + c0 + 1] = v3;
        }
        __syncthreads();

        // per-location 625-dot with register-resident bf16 weights
        #pragma unroll
        for (int s = 0; s < 10; ++s) {
            const int gbase = (s & 1) * EP_HALF + gb0 + (s >> 1);
            float acc = 0.f;
            #pragma unroll
            for (int k = 0; k < 5; ++k) {
                unsigned p = wpk[s][k];
                float e0 = Ep[gbase + offL[2*k]];
                float e1 = Ep[gbase + offL[2*k + 1]];
                acc = fmaf(e0, __uint_as_float(p << 16),         acc);
                acc = fmaf(e1, __uint_as_float(p & 0xffff0000u), acc);
            }
            acc = wred(acc);
            if (lane == 0) {
                float lat_neg = acc * isum_s[w*10 + s];
                float ec = Ep[gbase + 24*EWH + 12];
                float v = ec * 0.45f - lat_neg * 0.55f + aff_s[w*10 + s];
                v = tanhf(fmaxf(v, 0.f));
                dst[lbase + s] = v;
                lm_s[w*10 + s] += v;
            }
        }
        if (t < N_ITERS - 1) {
            __threadfence();
            grid.sync();
        }
    }

    // ================= publish lat_mean =================
    __syncthreads();
    for (int idx = tid; idx < LOCS; idx += BLK) {
        int r = idx / 20, cc = idx - 20 * r;
        ws[WS_LM + (i0 + r) * SHEET + (j0 + cc)] = lm_s[idx];
    }
    __threadfence();
    grid.sync();

    // ================= hebbian correlation =================
    // stage lat_mean tile (x0.1, pad HOMEO) into Ep (parity-split)
    for (int idx = tid; idx < EP_N; idx += BLK) {
        int p   = idx / EP_HALF;
        int rem = idx - p * EP_HALF;
        int yy  = rem / EWH;
        int col = rem - yy * EWH;
        int yg = i0 - 24 + yy;
        int xg = j0 - 24 + 2 * col + p;
        float v = HOMEO;
        if ((unsigned)yg < SHEET && (unsigned)xg < SHEET) v = ws[WS_LM + yg*SHEET + xg] * 0.1f;
        Ep[idx] = v;
    }
    __syncthreads();

    float wacc = 0.f;
    #pragma unroll
    for (int s = 0; s < 10; ++s) {
        const int gbase = (s & 1) * EP_HALF + gb0 + (s >> 1);
        float acc = 0.f;
        #pragma unroll
        for (int k = 0; k < 5; ++k) {
            unsigned p = wpk[s][k];
            float e0 = Ep[gbase + offL[2*k]];
            float e1 = Ep[gbase + offL[2*k + 1]];
            acc = fmaf(e0, __uint_as_float(p << 16),         acc);
            acc = fmaf(e1, __uint_as_float(p & 0xffff0000u), acc);
        }
        acc = wred(acc);
        if (lane == 0) {
            float lmv = lm_s[w*10 + s] * 0.1f;
            wacc += lmv * 62.5f * isum_s[w*10 + s] * acc;
        }
    }
    if (lane == 0) part_s[w] = wacc;
    __syncthreads();
    if (tid == 0) {
        float sm = 0.f;
        #pragma unroll
        for (int q = 0; q < NW; ++q) sm += part_s[q];
        ws[WS_PART + b] = sm;
    }
    __threadfence();
    grid.sync();

    // ================= deterministic final reduce (block 0) =================
    if (b == 0) {
        float v = (tid < GRID) ? ws[WS_PART + tid] : 0.f;
        Ep[tid] = v;
        if (tid < 1024 - BLK) Ep[BLK + tid] = 0.f;
        __syncthreads();
        #pragma unroll
        for (int s = 512; s > 0; s >>= 1) {
            if (tid < s) Ep[tid] += Ep[tid + s];
            __syncthreads();
        }
        if (tid == 0) out[2 * LTOT] = Ep[0];
    }
}

extern "C" void kernel_launch(void* const* d_in, const int* in_sizes, int n_in,
                              void* d_out, int out_size, void* d_ws, size_t ws_size,
                              hipStream_t stream) {
    const float* x    = (const float*)d_in[0];
    const float* rfs  = (const float*)d_in[1];
    const float* latw = (const float*)d_in[2];
    const float* ada  = (const float*)d_in[3];
    float* out = (float*)d_out;
    float* ws  = (float*)d_ws;

    void* args[] = { (void*)&x, (void*)&rfs, (void*)&latw, (void*)&ada,
                     (void*)&out, (void*)&ws };
    hipLaunchCooperativeKernel((void*)k_main, dim3(GRID), dim3(BLK),
                               args, 0, stream);
}

// Round 7
// 210.447 us; speedup vs baseline: 4.7151x; 4.7072x over previous
//
#include <hip/hip_runtime.h>
#include <math.h>

#define SHEET 160
#define LTOT (SHEET*SHEET)          // 25600
#define F_AFF 450
#define F_LAT 625
#define N_ITERS 10
#define IN_HW 174                   // SHEET + AFF_K - 1
#define HOMEO 0.02f
#define PI_D 3.14159265358979323846

// ---- lateral tile geometry: 4 rows x 16 cols of locations per block ----
#define BH 4
#define BW 16
#define BLK 512                     // 8 waves, each handles 8 locations
#define GRID_L ((SHEET/BH)*(SHEET/BW))  // 40*10 = 400 blocks
#define EH 52                       // BH + 48 E-field rows
#define EWH 33                      // (BW+48)/2 + 1 pad (parity-half width)
#define EP_HALF (EH*EWH)            // 1716
#define EP_N (2*EP_HALF)            // 3432
#define LW 69                       // BW+52=68 cols, padded to 69
#define LH 56                       // BH + 52
#define LT_N (LH*LW)                // 3864

// afferent / pack geometry: wave-per-location
#define AWPB 8
#define ABLK (AWPB*64)
#define ANBLK (LTOT/AWPB)           // 3200

// ---- workspace layout (float offsets) ----
#define WS_SRE    0                 // 32 (25 used)
#define WS_LATTAB 32                // float2[640] {lri, off}
#define WS_AFFTAB 1312              // float2[512] {env, off}
#define WS_AFF    2336
#define WS_B0     (WS_AFF + LTOT)
#define WS_B1     (WS_B0  + LTOT)
#define WS_LM     (WS_B1  + LTOT)
#define WS_PART   (WS_LM  + LTOT)   // GRID_L floats (pad 512)
#define WS_WQ     (WS_PART + 512)   // 25600*320 u32 = 32.768 MB (ws is ~256 MB)

__device__ __forceinline__ float wred(float v) {
    #pragma unroll
    for (int m = 32; m > 0; m >>= 1) v += __shfl_xor(v, m, 64);
    return v;
}

__device__ __forceinline__ unsigned f2bf(float f) {   // RNE float->bf16 bits
    unsigned u = __float_as_uint(f);
    return (u + 0x7FFFu + ((u >> 16) & 1u)) >> 16;
}

// ---------------- init: constant tables ----------------
__global__ __launch_bounds__(1024) void k_init(float* __restrict__ ws) {
    __shared__ float red[1024];
    const int t = threadIdx.x;

    float sre_raw = 0.f;
    if (t < 25) {
        int u = t / 5, v = t % 5;
        double d = sqrt((double)((u-2)*(u-2) + (v-2)*(v-2)));
        if (d < 2.5) { double cv = cos(fmin(d/5.0, 1.0) * PI_D * 0.5); sre_raw = (float)(cv*cv); }
    }

    float lri_raw = 0.f;
    const int dy = t / 25, dx = t % 25;
    if (t < 625) {
        double d = sqrt((double)((dy-12)*(dy-12) + (dx-12)*(dx-12)));
        double base = 0.0, inh = 0.0;
        if (d < 12.5) { double cv = cos(fmin(d/25.0, 1.0) * PI_D * 0.5); base = cv*cv; }
        if (d < 1.25) { double cv = cos(fmin(d/2.5,  1.0) * PI_D * 0.5); inh  = cv*cv; }
        lri_raw = (float)(base * (1.0 - inh));
    }

    red[t] = lri_raw;
    __syncthreads();
    #pragma unroll
    for (int s = 512; s > 0; s >>= 1) {
        if (t < s) red[t] = fmaxf(red[t], red[t + s]);
        __syncthreads();
    }
    const float lri_max = red[0];
    __syncthreads();

    red[t] = sre_raw;
    __syncthreads();
    #pragma unroll
    for (int s = 512; s > 0; s >>= 1) {
        if (t < s) red[t] += red[t + s];
        __syncthreads();
    }
    const float sre_sum = red[0];

    if (t < 32) ws[WS_SRE + t] = (t < 25) ? sre_raw / sre_sum : 0.f;

    // lateral table: {lri_norm, gather offset dy*(2*EWH)+dx}; lri=0 for t>=625
    if (t < 640) {
        float lv = (t < 625) ? lri_raw / lri_max : 0.f;
        int  off = (t < 625) ? (dy * (2*EWH) + dx) : 0;
        ((float2*)(ws + WS_LATTAB))[t] = make_float2(lv, __int_as_float(off));
    }

    // afferent table: {env, x offset}
    if (t < 512) {
        float ev = 0.f; int off = 0;
        if (t < 450) {
            int c  = t / 225, rr = t % 225;
            int kh = rr / 15, kw = rr % 15;
            double d = sqrt((double)((kh-7)*(kh-7) + (kw-7)*(kw-7)));
            if (d < 7.5) { double cv = cos(fmin(d/15.0, 1.0) * PI_D * 0.5); ev = (float)(cv*cv); }
            off = c * (IN_HW*IN_HW) + kh * IN_HW + kw;
        }
        ((float2*)(ws + WS_AFFTAB))[t] = make_float2(ev, __int_as_float(off));
    }
}

// ---------------- fused afferent pass + weight pack ----------------
// blocks [0, ANBLK): afferent (rfs stream). blocks [ANBLK, 2*ANBLK): latw pack.
__global__ __launch_bounds__(ABLK) void k_pre(const float* __restrict__ x,
                                              const float* __restrict__ rfs,
                                              const float* __restrict__ latw,
                                              const float* __restrict__ ada,
                                              float* __restrict__ out_rawaff,
                                              float* __restrict__ ws,
                                              unsigned* __restrict__ wq) {
    const int w = threadIdx.x >> 6, lane = threadIdx.x & 63;

    if (blockIdx.x < ANBLK) {
        const float2* tab = (const float2*)(ws + WS_AFFTAB);
        const int l = blockIdx.x * AWPB + w;
        const int i = l / SHEET, j = l % SHEET;
        const int xbase = i * IN_HW + j;
        const float* rrow = rfs + (size_t)l * F_AFF;

        float dot = 0.f, sum = 0.f;
        #pragma unroll
        for (int it = 0; it < 8; ++it) {
            int f = it * 64 + lane;
            float2 tb = tab[f];
            int   fc = (f < F_AFF) ? f : 0;
            float rv = rrow[fc];
            if (f >= F_AFF) rv = 0.f;
            float xv = x[xbase + __float_as_int(tb.y)];
            dot = fmaf(xv * tb.x, rv, dot);
            sum += rv;
        }
        dot = wred(dot);
        sum = wred(sum);
        if (lane == 0) {
            float a = dot / sum;
            out_rawaff[l] = 45.0f * a;                 // raw_aff
            float aff = a - ada[l];
            ws[WS_AFF + l] = aff;
            ws[WS_B0  + l] = fmaxf(aff, 0.f);          // lat_0 = relu(aff)
            ws[WS_LM  + l] = 0.f;
        }
    } else {
        // pack: wq[l*320 + k*64 + lane] = bf16(w[f]*lri[f]/sum) | bf16(w[f+320]*lri[f+320]/sum)<<16
        // with f = k*64+lane, k = 0..4  (pair layout (f, f+320): stride-1 LDS gathers)
        const int l = (blockIdx.x - ANBLK) * AWPB + w;
        const float* wrow = latw + (size_t)l * F_LAT;
        const float2* tab = (const float2*)(ws + WS_LATTAB);

        float wv[10], lri[10], sum = 0.f;
        #pragma unroll
        for (int it = 0; it < 10; ++it) {
            int f = it * 64 + lane;
            lri[it] = tab[f].x;                        // 0 for f >= 625
            int fc = (f < F_LAT) ? f : 0;
            float v = wrow[fc];
            if (f >= F_LAT) v = 0.f;
            wv[it] = v;
            sum += v;
        }
        sum = wred(sum);
        const float inv = 1.0f / sum;

        unsigned* dst = wq + (size_t)l * 320;
        #pragma unroll
        for (int k = 0; k < 5; ++k) {
            unsigned lo = f2bf(wv[k]     * lri[k]     * inv);
            unsigned hi = f2bf(wv[k + 5] * lri[k + 5] * inv);
            dst[k * 64 + lane] = lo | (hi << 16);
        }
    }
}

// ---------------- lateral iteration: fused 5x5 conv + 625-dot (bf16 packed weights) ----------------
__global__ __launch_bounds__(BLK, 4) void k_lat(const unsigned* __restrict__ wq,
                                                float* __restrict__ ws,
                                                const float* __restrict__ lsrc,
                                                float* __restrict__ lat_out) {
    __shared__ float Lt[LT_N];
    __shared__ float Ep[EP_N];
    const int b  = blockIdx.x;
    const int i0 = (b / (SHEET/BW)) * BH;
    const int j0 = (b % (SHEET/BW)) * BW;
    const int tid = threadIdx.x;
    const int w = tid >> 6, lane = tid & 63;

    const float* sre_g = ws + WS_SRE;

    for (int idx = tid; idx < LT_N; idx += BLK) {
        int r = idx / LW, c = idx - r * LW;
        int y  = i0 + r - 26;
        int xx = j0 + c - 26;
        float v = HOMEO;
        if (c < 68 && (unsigned)y < SHEET && (unsigned)xx < SHEET) v = lsrc[y*SHEET + xx];
        Lt[idx] = v;
    }

    const float2* tab = (const float2*)(ws + WS_LATTAB);
    int off_reg[10];
    #pragma unroll
    for (int it = 0; it < 10; ++it) off_reg[it] = __float_as_int(tab[it * 64 + lane].y);
    __syncthreads();

    for (int qi = tid; qi < EH * 16; qi += BLK) {
        int q = qi & 15, y = qi >> 4;
        int x0 = q * 4;
        float a0 = 0.f, a1 = 0.f, a2 = 0.f, a3 = 0.f;
        #pragma unroll
        for (int u = 0; u < 5; ++u) {
            const float* row = &Lt[(y + u) * LW + x0];
            float ra[8];
            #pragma unroll
            for (int v = 0; v < 8; ++v) ra[v] = row[v];
            #pragma unroll
            for (int v = 0; v < 5; ++v) {
                float s = sre_g[u * 5 + v];
                a0 = fmaf(ra[v],     s, a0);
                a1 = fmaf(ra[v + 1], s, a1);
                a2 = fmaf(ra[v + 2], s, a2);
                a3 = fmaf(ra[v + 3], s, a3);
            }
        }
        int yg = i0 - 24 + y;
        bool yok = (unsigned)yg < SHEET;
        int xg = j0 - 24 + x0;
        float v0 = (yok && (unsigned)(xg    ) < SHEET) ? a0 : HOMEO;
        float v1 = (yok && (unsigned)(xg + 1) < SHEET) ? a1 : HOMEO;
        float v2 = (yok && (unsigned)(xg + 2) < SHEET) ? a2 : HOMEO;
        float v3 = (yok && (unsigned)(xg + 3) < SHEET) ? a3 : HOMEO;
        int c0 = y * EWH + 2 * q;
        Ep[c0]               = v0;
        Ep[EP_HALF + c0]     = v1;
        Ep[c0 + 1]           = v2;
        Ep[EP_HALF + c0 + 1] = v3;
    }
    __syncthreads();

    #pragma unroll 2
    for (int s = 0; s < 8; ++s) {
        int li = w * 8 + s;
        int r  = li >> 4, cc = li & 15;
        int l  = (i0 + r) * SHEET + (j0 + cc);
        const unsigned* wrow = wq + (size_t)l * 320;
        int gbase = (cc & 1) * EP_HALF + r * EWH + (cc >> 1);

        float acc = 0.f;
        #pragma unroll
        for (int k = 0; k < 5; ++k) {
            unsigned p = wrow[k * 64 + lane];
            float e0 = Ep[gbase + off_reg[k]];
            float e1 = Ep[gbase + off_reg[k + 5]];
            acc = fmaf(e0, __uint_as_float(p << 16),         acc);
            acc = fmaf(e1, __uint_as_float(p & 0xffff0000u), acc);
        }
        acc = wred(acc);

        if (lane == 0) {
            float ec = Ep[gbase + 24*EWH + 12];
            float v = ec * 0.45f - acc * 0.55f + ws[WS_AFF + l];
            v = tanhf(fmaxf(v, 0.f));
            lat_out[l] = v;
            ws[WS_LM + l] += v;
        }
    }
}

// ---------------- hebbian correlation ----------------
__global__ __launch_bounds__(BLK, 4) void k_hebb(const unsigned* __restrict__ wq,
                                                 float* __restrict__ ws) {
    __shared__ float LMp[EP_N];
    __shared__ float part[8];
    const int b  = blockIdx.x;
    const int i0 = (b / (SHEET/BW)) * BH;
    const int j0 = (b % (SHEET/BW)) * BW;
    const int tid = threadIdx.x;
    const int w = tid >> 6, lane = tid & 63;
    const float* lm = ws + WS_LM;

    for (int idx = tid; idx < EP_N; idx += BLK) {
        int p   = idx / EP_HALF;
        int rem = idx - p * EP_HALF;
        int y   = rem / EWH;
        int col = rem - y * EWH;
        int yg = i0 - 24 + y;
        int xg = j0 - 24 + 2 * col + p;
        float v = HOMEO;
        if ((unsigned)yg < SHEET && (unsigned)xg < SHEET) v = lm[yg*SHEET + xg] * 0.1f;
        LMp[idx] = v;
    }

    const float2* tab = (const float2*)(ws + WS_LATTAB);
    int off_reg[10];
    #pragma unroll
    for (int it = 0; it < 10; ++it) off_reg[it] = __float_as_int(tab[it * 64 + lane].y);
    __syncthreads();

    float wacc = 0.f;
    #pragma unroll 2
    for (int s = 0; s < 8; ++s) {
        int li = w * 8 + s;
        int r  = li >> 4, cc = li & 15;
        int l  = (i0 + r) * SHEET + (j0 + cc);
        const unsigned* wrow = wq + (size_t)l * 320;
        int gbase = (cc & 1) * EP_HALF + r * EWH + (cc >> 1);

        float acc = 0.f;
        #pragma unroll
        for (int k = 0; k < 5; ++k) {
            unsigned p = wrow[k * 64 + lane];
            float e0 = LMp[gbase + off_reg[k]];
            float e1 = LMp[gbase + off_reg[k + 5]];
            acc = fmaf(e0, __uint_as_float(p << 16),         acc);
            acc = fmaf(e1, __uint_as_float(p & 0xffff0000u), acc);
        }
        acc = wred(acc);
        if (lane == 0) {
            float lmv = LMp[gbase + 24*EWH + 12];      // lat_mean[l] * 0.1
            wacc += lmv * 62.5f * acc;
        }
    }
    if (lane == 0) part[w] = wacc;
    __syncthreads();
    if (tid == 0) {
        float s = 0.f;
        #pragma unroll
        for (int q = 0; q < 8; ++q) s += part[q];
        ws[WS_PART + b] = s;
    }
}

// ---------------- deterministic final reduce ----------------
__global__ __launch_bounds__(1024) void k_final(const float* __restrict__ ws,
                                                float* __restrict__ out_scalar) {
    __shared__ float red[1024];
    float s = 0.f;
    for (int idx = threadIdx.x; idx < GRID_L; idx += 1024) s += ws[WS_PART + idx];
    red[threadIdx.x] = s;
    __syncthreads();
    #pragma unroll
    for (int st = 512; st > 0; st >>= 1) {
        if (threadIdx.x < st) red[threadIdx.x] += red[threadIdx.x + st];
        __syncthreads();
    }
    if (threadIdx.x == 0) *out_scalar = red[0];
}

extern "C" void kernel_launch(void* const* d_in, const int* in_sizes, int n_in,
                              void* d_out, int out_size, void* d_ws, size_t ws_size,
                              hipStream_t stream) {
    const float* x    = (const float*)d_in[0];
    const float* rfs  = (const float*)d_in[1];
    const float* latw = (const float*)d_in[2];
    const float* ada  = (const float*)d_in[3];
    float* out = (float*)d_out;
    float* ws  = (float*)d_ws;
    unsigned* wq = (unsigned*)(ws + WS_WQ);

    k_init<<<1, 1024, 0, stream>>>(ws);
    k_pre<<<2 * ANBLK, ABLK, 0, stream>>>(x, rfs, latw, ada, out, ws, wq);

    for (int t = 0; t < N_ITERS; ++t) {
        const float* src = ws + ((t & 1) ? WS_B1 : WS_B0);
        float* dst = (t == N_ITERS - 1) ? (out + LTOT)
                                        : (ws + ((t & 1) ? WS_B0 : WS_B1));
        k_lat<<<GRID_L, BLK, 0, stream>>>(wq, ws, src, dst);
    }

    k_hebb<<<GRID_L, BLK, 0, stream>>>(wq, ws);
    k_final<<<1, 1024, 0, stream>>>(ws, out + 2 * LTOT);
}